// Round 7
// baseline (5058.894 us; speedup 1.0000x reference)
//
#include <hip/hip_runtime.h>
#include <math.h>

#define E_DIM 768
#define NTOK 1025
#define B_DIM 32
#define NHEADS 12
#define HDIM 64
#define LAYERS 12
#define FF_DIM 3072
#define P2 576
#define GRID 384

// ---------------- helpers ----------------
__device__ __forceinline__ float block_reduce_sum(float v, float* red) {
  int tid = threadIdx.x;
  red[tid] = v;
  __syncthreads();
#pragma unroll
  for (int s = 128; s > 0; s >>= 1) {
    if (tid < s) red[tid] += red[tid + s];
    __syncthreads();
  }
  float r = red[0];
  __syncthreads();
  return r;
}

// device-scope grid barrier: monotone counter, bounded spin.
// All GRID blocks must call in identical sequence. Counter zeroed each launch.
__device__ __forceinline__ void grid_barrier(unsigned* cnt, unsigned target) {
  __syncthreads();
  if (threadIdx.x == 0) {
    __threadfence();                 // release: prior stores visible device-wide
    atomicAdd(cnt, 1u);
    unsigned it = 0;
    while (atomicAdd(cnt, 0u) < target) {   // device-scope poll (cross-XCD coherent)
      if (++it > 200000u) break;            // bounded: fail loud, not hang
      __builtin_amdgcn_s_sleep(2);
    }
    __threadfence();                 // acquire: invalidate stale cached lines
  }
  __syncthreads();
}

// ---------------- setup kernels (unchanged, proven) ----------------
__global__ __launch_bounds__(256) void embed_gemm(
    const float* __restrict__ A, const float* __restrict__ W,
    const float* __restrict__ bias, const float* __restrict__ pos,
    float* __restrict__ scene) {
  __shared__ float Xs[16][132];
  __shared__ float Ws[16][132];
  int tid = threadIdx.x;
  int n0 = blockIdx.x * 128;
  int m0 = blockIdx.y * 128;
  int lr = tid >> 2;
  int lk = (tid & 3) << 2;
  int ty = tid >> 4, tx = tid & 15;
  float acc[8][8] = {};
  for (int k0 = 0; k0 < P2; k0 += 16) {
    float4 x0 = *(const float4*)(A + (size_t)(m0 + lr) * P2 + k0 + lk);
    float4 x1 = *(const float4*)(A + (size_t)(m0 + 64 + lr) * P2 + k0 + lk);
    float4 w0 = *(const float4*)(W + (size_t)(n0 + lr) * P2 + k0 + lk);
    float4 w1 = *(const float4*)(W + (size_t)(n0 + 64 + lr) * P2 + k0 + lk);
    __syncthreads();
    Xs[lk + 0][lr] = x0.x; Xs[lk + 1][lr] = x0.y; Xs[lk + 2][lr] = x0.z; Xs[lk + 3][lr] = x0.w;
    Xs[lk + 0][64 + lr] = x1.x; Xs[lk + 1][64 + lr] = x1.y; Xs[lk + 2][64 + lr] = x1.z; Xs[lk + 3][64 + lr] = x1.w;
    Ws[lk + 0][lr] = w0.x; Ws[lk + 1][lr] = w0.y; Ws[lk + 2][lr] = w0.z; Ws[lk + 3][lr] = w0.w;
    Ws[lk + 0][64 + lr] = w1.x; Ws[lk + 1][64 + lr] = w1.y; Ws[lk + 2][64 + lr] = w1.z; Ws[lk + 3][64 + lr] = w1.w;
    __syncthreads();
#pragma unroll
    for (int kk = 0; kk < 16; ++kk) {
      float4 a0 = *(const float4*)&Xs[kk][ty << 2];
      float4 a1 = *(const float4*)&Xs[kk][64 + (ty << 2)];
      float4 b0 = *(const float4*)&Ws[kk][tx << 2];
      float4 b1 = *(const float4*)&Ws[kk][64 + (tx << 2)];
      float av[8] = {a0.x, a0.y, a0.z, a0.w, a1.x, a1.y, a1.z, a1.w};
      float bv[8] = {b0.x, b0.y, b0.z, b0.w, b1.x, b1.y, b1.z, b1.w};
#pragma unroll
      for (int i = 0; i < 8; ++i)
#pragma unroll
        for (int j = 0; j < 8; ++j) acc[i][j] += av[i] * bv[j];
    }
  }
#pragma unroll
  for (int i = 0; i < 8; ++i) {
    int mloc = (i < 4) ? ((ty << 2) + i) : (64 + (ty << 2) + i - 4);
    int m = m0 + mloc;
    int b = m >> 10, nt = m & 1023;
    size_t row = ((size_t)b * NTOK + 1 + nt) * E_DIM;
    size_t prow = (size_t)(1 + nt) * E_DIM;
#pragma unroll
    for (int half = 0; half < 2; ++half) {
      int n = n0 + half * 64 + (tx << 2);
      float4 o4;
      o4.x = acc[i][half * 4 + 0] + bias[n + 0] + pos[prow + n + 0];
      o4.y = acc[i][half * 4 + 1] + bias[n + 1] + pos[prow + n + 1];
      o4.z = acc[i][half * 4 + 2] + bias[n + 2] + pos[prow + n + 2];
      o4.w = acc[i][half * 4 + 3] + bias[n + 3] + pos[prow + n + 3];
      *(float4*)&scene[row + n] = o4;
    }
  }
}

__global__ void scene_cls(const float* __restrict__ cls, const float* __restrict__ pos,
                          float* __restrict__ scene) {
  int b = blockIdx.x;
  for (int e = threadIdx.x; e < E_DIM; e += 256)
    scene[(size_t)b * NTOK * E_DIM + e] = cls[e] + pos[e];
}

__global__ __launch_bounds__(256) void ln_rows(const float* __restrict__ in, float* __restrict__ out) {
  __shared__ float red[256];
  int r = blockIdx.x, tid = threadIdx.x;
  const float* x = in + (size_t)r * E_DIM;
  float a0 = x[tid], a1 = x[tid + 256], a2 = x[tid + 512];
  float mean = block_reduce_sum(a0 + a1 + a2, red) * (1.f / 768.f);
  float d0 = a0 - mean, d1 = a1 - mean, d2 = a2 - mean;
  float var = block_reduce_sum(d0 * d0 + d1 * d1 + d2 * d2, red) * (1.f / 768.f);
  float rinv = rsqrtf(var + 1e-5f);
  float* o = out + (size_t)r * E_DIM;
  o[tid] = d0 * rinv; o[tid + 256] = d1 * rinv; o[tid + 512] = d2 * rinv;
}

__global__ __launch_bounds__(256) void tgt_init(
    const float* __restrict__ tmask, const float* __restrict__ W,
    const float* __restrict__ bias, const float* __restrict__ cls,
    const float* __restrict__ tpos, float* __restrict__ tq) {
  int b = blockIdx.x, tid = threadIdx.x;
  for (int e = tid; e < E_DIM; e += 256)
    tq[(size_t)(b * 2) * E_DIM + e] = cls[e] + tpos[e];
  const float* tm = tmask + (size_t)b * P2;
  for (int e = tid; e < E_DIM; e += 256) {
    const float* wr = W + (size_t)e * P2;
    float s = 0.f;
    for (int k = 0; k < P2; k += 4) {
      float4 w4 = *(const float4*)&wr[k];
      float4 t4 = *(const float4*)&tm[k];
      s += w4.x * t4.x + w4.y * t4.y + w4.z * t4.z + w4.w * t4.w;
    }
    tq[(size_t)(b * 2 + 1) * E_DIM + e] = s + bias[e] + tpos[E_DIM + e];
  }
}

__global__ void prep_m(const float* __restrict__ Wq, const float* __restrict__ Wk,
                       float* __restrict__ Mb) {
  int l = blockIdx.y;
  int idx = blockIdx.x * 256 + threadIdx.x;
  int d = idx >> 6, dp = idx & 63;
  const float* wq = Wq + l * 4096;
  const float* wk = Wk + l * 4096;
  float s = 0.f;
#pragma unroll 8
  for (int e = 0; e < 64; ++e) s += wq[e * 64 + d] * wk[e * 64 + dp];
  Mb[l * 4096 + idx] = s;
}

__global__ void prep_wvo(const float* __restrict__ Wv, const float* __restrict__ Wo,
                         float* __restrict__ Wvo) {
  int l = blockIdx.y;
  int idx = blockIdx.x * 256 + threadIdx.x;
  int ep = idx / 768, hd = idx % 768;
  int h = hd >> 6, d = hd & 63;
  const float* wv = Wv + (size_t)l * 4096;
  const float* wo = Wo + (size_t)l * 768 * 768 + (size_t)ep * 768 + h * 64;
  float s = 0.f;
#pragma unroll 8
  for (int ev = 0; ev < 64; ++ev) s += wv[ev * 64 + d] * wo[ev];
  Wvo[(size_t)l * 589824 + idx] = s;
}

// ---------------- shared-memory stage structs ----------------
struct GemmS { float Xs[16][64]; float Ws[16][64]; };
struct AttnS { float red[256]; float sred[2][16]; float cred[2][16][64]; };
struct LnS   { float red[256]; float q[768]; float qm[768]; };
struct TopS  { float v[1024]; float bv[256]; int bi[256]; };

// ---------------- device stage functions (bodies proven in rounds 3-6) ----------------
__device__ void dev_qproj(LnS& L, int m, const float* gl, const float* bl,
                          const float* M, float* qMg, float* qMb) {
  int tid = threadIdx.x;
  const float inv_scale = rsqrtf(768.f);
  for (int o = tid; o < 768; o += 256) {
    int h = o >> 6, dp = o & 63;
    const float* qh = L.q + h * 64;
    float s = 0.f;
#pragma unroll 8
    for (int d = 0; d < 64; ++d) s += qh[d] * M[d * 64 + dp];
    L.qm[o] = s;
    qMg[(size_t)m * E_DIM + o] = s * gl[o] * inv_scale;
  }
  __syncthreads();
  if (tid < NHEADS) {
    float acc = 0.f;
#pragma unroll 8
    for (int dp = 0; dp < 64; ++dp) acc += L.qm[tid * 64 + dp] * bl[tid * 64 + dp];
    qMb[m * NHEADS + tid] = acc * inv_scale;
  }
}

__device__ void dev_qln0(LnS& L, int m, const float* tq, const float* g1,
                         const float* b1, const float* Mb, float* qMg, float* qMb) {
  int tid = threadIdx.x;
  const float* x = tq + (size_t)m * E_DIM;
  float a0 = x[tid], a1 = x[tid + 256], a2 = x[tid + 512];
  float mean = block_reduce_sum(a0 + a1 + a2, L.red) * (1.f / 768.f);
  float d0 = a0 - mean, d1 = a1 - mean, d2 = a2 - mean;
  float var = block_reduce_sum(d0 * d0 + d1 * d1 + d2 * d2, L.red) * (1.f / 768.f);
  float rinv = rsqrtf(var + 1e-5f);
  L.q[tid] = d0 * rinv * g1[tid] + b1[tid];
  L.q[tid + 256] = d1 * rinv * g1[tid + 256] + b1[tid + 256];
  L.q[tid + 512] = d2 * rinv * g1[tid + 512] + b1[tid + 512];
  __syncthreads();
  dev_qproj(L, m, g1, b1, Mb, qMg, qMb);
}

#define ACH 272
__device__ void dev_attn(AttnS& A, const float* __restrict__ ns,
                         const float* __restrict__ qMg, const float* __restrict__ qMb,
                         const float* __restrict__ g1, const float* __restrict__ b1,
                         int l, float* __restrict__ ctx, int bid) {
  int b = bid / NHEADS;
  int h = bid % NHEADS;
  int tid = threadIdx.x;
  int g = tid >> 4;
  int lane = tid & 15;
  int r0 = b * 2, r1 = r0 + 1;
  const float* nsb = ns + (size_t)b * NTOK * E_DIM + h * 64;
  float4 q0v = *(const float4*)(qMg + (size_t)r0 * E_DIM + h * 64 + lane * 4);
  float4 q1v = *(const float4*)(qMg + (size_t)r1 * E_DIM + h * 64 + lane * 4);
  float qb0 = qMb[r0 * NHEADS + h], qb1 = qMb[r1 * NHEADS + h];
  float m = -1e30f, s0 = 0.f, s1 = 0.f;
  float4 c0 = {0, 0, 0, 0}, c1 = {0, 0, 0, 0};
  float4 v[17];
  float e0a[17], e1a[17];
  for (int cb = 0; cb < NTOK; cb += ACH) {
    int ntk = NTOK - cb; if (ntk > ACH) ntk = ACH;
    int cnt = (ntk - g + 15) >> 4;
    float mloc = -1e30f;
#pragma unroll
    for (int i = 0; i < 17; ++i) {
      if (i < cnt) {
        int k = cb + g + (i << 4);
        float4 vv = *(const float4*)(nsb + (size_t)k * E_DIM + lane * 4);
        v[i] = vv;
        float p0 = vv.x * q0v.x + vv.y * q0v.y + vv.z * q0v.z + vv.w * q0v.w;
        float p1 = vv.x * q1v.x + vv.y * q1v.y + vv.z * q1v.z + vv.w * q1v.w;
#pragma unroll
        for (int off = 8; off; off >>= 1) {
          p0 += __shfl_xor(p0, off, 16);
          p1 += __shfl_xor(p1, off, 16);
        }
        float e0 = p0 + qb0, e1 = p1 + qb1;
        e0a[i] = e0; e1a[i] = e1;
        mloc = fmaxf(mloc, fmaxf(e0, e1));
      }
    }
    A.red[tid] = mloc;
    __syncthreads();
#pragma unroll
    for (int s = 128; s > 0; s >>= 1) {
      if (tid < s) A.red[tid] = fmaxf(A.red[tid], A.red[tid + s]);
      __syncthreads();
    }
    float mnew = fmaxf(m, A.red[0]);
    __syncthreads();
    if (mnew > m) {
      float f = expf(m - mnew);
      s0 *= f; s1 *= f;
      c0.x *= f; c0.y *= f; c0.z *= f; c0.w *= f;
      c1.x *= f; c1.y *= f; c1.z *= f; c1.w *= f;
      m = mnew;
    }
#pragma unroll
    for (int i = 0; i < 17; ++i) {
      if (i < cnt) {
        float p0 = expf(e0a[i] - m);
        float p1 = expf(e1a[i] - m);
        s0 += p0; s1 += p1;
        c0.x += p0 * v[i].x; c0.y += p0 * v[i].y; c0.z += p0 * v[i].z; c0.w += p0 * v[i].w;
        c1.x += p1 * v[i].x; c1.y += p1 * v[i].y; c1.z += p1 * v[i].z; c1.w += p1 * v[i].w;
      }
    }
  }
  if (lane == 0) { A.sred[0][g] = s0; A.sred[1][g] = s1; }
  *(float4*)&A.cred[0][g][lane * 4] = c0;
  *(float4*)&A.cred[1][g][lane * 4] = c1;
  __syncthreads();
  if (tid < 128) {
    int t = tid >> 6, dd = tid & 63;
    int o = h * 64 + dd;
    float stot = 0.f, cs = 0.f;
#pragma unroll
    for (int gg = 0; gg < 16; ++gg) { stot += A.sred[t][gg]; cs += A.cred[t][gg][dd]; }
    float inv = 1.f / stot;
    ctx[(size_t)(r0 + t) * E_DIM + o] = cs * inv * g1[l * E_DIM + o] + b1[l * E_DIM + o];
  }
}

__device__ void dev_skinny(GemmS& G, const float* X, int K, const float* W,
                           int kchunk, float* part, int N, int n0, int s) {
  int tid = threadIdx.x;
  int kbeg = s * kchunk;
  int lr = tid >> 2;
  int lk = (tid & 3) << 2;
  int ty = tid >> 4, tx = tid & 15;
  float acc[4][4] = {};
  for (int k0 = kbeg; k0 < kbeg + kchunk; k0 += 16) {
    float4 xv = *(const float4*)(X + (size_t)lr * K + k0 + lk);
    float4 wv = *(const float4*)(W + (size_t)(n0 + lr) * K + k0 + lk);
    __syncthreads();
    G.Xs[lk + 0][lr] = xv.x; G.Xs[lk + 1][lr] = xv.y; G.Xs[lk + 2][lr] = xv.z; G.Xs[lk + 3][lr] = xv.w;
    G.Ws[lk + 0][lr] = wv.x; G.Ws[lk + 1][lr] = wv.y; G.Ws[lk + 2][lr] = wv.z; G.Ws[lk + 3][lr] = wv.w;
    __syncthreads();
#pragma unroll
    for (int kk = 0; kk < 16; ++kk) {
      float4 a4 = *(const float4*)&G.Xs[kk][ty << 2];
      float4 b4 = *(const float4*)&G.Ws[kk][tx << 2];
      float av[4] = {a4.x, a4.y, a4.z, a4.w};
      float bv[4] = {b4.x, b4.y, b4.z, b4.w};
#pragma unroll
      for (int i = 0; i < 4; ++i)
#pragma unroll
        for (int j = 0; j < 4; ++j) acc[i][j] += av[i] * bv[j];
    }
  }
#pragma unroll
  for (int i = 0; i < 4; ++i) {
    int mm = (ty << 2) + i;
    float4 o4 = make_float4(acc[i][0], acc[i][1], acc[i][2], acc[i][3]);
    *(float4*)&part[((size_t)s * 64 + mm) * N + n0 + (tx << 2)] = o4;
  }
}

__device__ void dev_reduce_bias(const float* part, int S, int N,
                                const float* bias, int relu, float* out, int m) {
  for (int n = threadIdx.x; n < N; n += 256) {
    float s = 0.f;
    for (int i = 0; i < S; ++i) s += part[((size_t)i * 64 + m) * N + n];
    s += bias[n];
    if (relu) s = fmaxf(s, 0.f);
    out[(size_t)m * N + n] = s;
  }
}

__device__ void dev_reduce_ln_q(LnS& L, const float* part, int S, const float* bias,
                                const float* res, const float* g, const float* bsh,
                                float* out, const float* Mb_next, const float* g1n,
                                const float* b1n, float* qMg, float* qMb,
                                float* xmean, int m) {
  int tid = threadIdx.x;
  float t[3];
#pragma unroll
  for (int c = 0; c < 3; ++c) {
    int n = tid + c * 256;
    float s = 0.f;
    for (int i = 0; i < S; ++i) s += part[((size_t)i * 64 + m) * 768 + n];
    t[c] = s + bias[n] + res[(size_t)m * 768 + n];
  }
  float mean = block_reduce_sum(t[0] + t[1] + t[2], L.red) * (1.f / 768.f);
  float d0 = t[0] - mean, d1 = t[1] - mean, d2 = t[2] - mean;
  float var = block_reduce_sum(d0 * d0 + d1 * d1 + d2 * d2, L.red) * (1.f / 768.f);
  float rinv = rsqrtf(var + 1e-5f);
  float y0 = d0 * rinv * g[tid] + bsh[tid];
  float y1 = d1 * rinv * g[tid + 256] + bsh[tid + 256];
  float y2 = d2 * rinv * g[tid + 512] + bsh[tid + 512];
  out[(size_t)m * 768 + tid] = y0;
  out[(size_t)m * 768 + tid + 256] = y1;
  out[(size_t)m * 768 + tid + 512] = y2;
  if (xmean) {
    float* xr = xmean + (size_t)(m >> 1) * 768;
    atomicAdd(&xr[tid], 0.5f * y0);
    atomicAdd(&xr[tid + 256], 0.5f * y1);
    atomicAdd(&xr[tid + 512], 0.5f * y2);
  }
  if (Mb_next) {
    float mean2 = block_reduce_sum(y0 + y1 + y2, L.red) * (1.f / 768.f);
    float e0 = y0 - mean2, e1 = y1 - mean2, e2 = y2 - mean2;
    float var2 = block_reduce_sum(e0 * e0 + e1 * e1 + e2 * e2, L.red) * (1.f / 768.f);
    float rinv2 = rsqrtf(var2 + 1e-5f);
    L.q[tid] = e0 * rinv2 * g1n[tid] + b1n[tid];
    L.q[tid + 256] = e1 * rinv2 * g1n[tid + 256] + b1n[tid + 256];
    L.q[tid + 512] = e2 * rinv2 * g1n[tid + 512] + b1n[tid + 512];
    __syncthreads();
    dev_qproj(L, m, g1n, b1n, Mb_next, qMg, qMb);
  }
}

__device__ void dev_top5(TopS& T, const float* part, const float* bias,
                         float* out, int b) {
  int tid = threadIdx.x;
  for (int i = tid; i < 1024; i += 256) {
    float s = part[(size_t)(0 * 64 + b) * 1024 + i] + part[(size_t)(1 * 64 + b) * 1024 + i] +
              part[(size_t)(2 * 64 + b) * 1024 + i] + part[(size_t)(3 * 64 + b) * 1024 + i];
    T.v[i] = s + bias[i];
  }
  float* ob = out + (size_t)b * 5 * NTOK;
  for (int i = tid; i < 5 * NTOK; i += 256) ob[i] = 0.f;
  __syncthreads();
  for (int it = 0; it < 5; ++it) {
    float best = -1e38f;
    int bidx = 0x7fffffff;
    for (int i = tid; i < 1024; i += 256) {
      float x = T.v[i];
      if (x > best || (x == best && i < bidx)) { best = x; bidx = i; }
    }
    T.bv[tid] = best; T.bi[tid] = bidx;
    __syncthreads();
    for (int s = 128; s > 0; s >>= 1) {
      if (tid < s) {
        if (T.bv[tid + s] > T.bv[tid] ||
            (T.bv[tid + s] == T.bv[tid] && T.bi[tid + s] < T.bi[tid])) {
          T.bv[tid] = T.bv[tid + s]; T.bi[tid] = T.bi[tid + s];
        }
      }
      __syncthreads();
    }
    if (tid == 0) {
      ob[it * NTOK + T.bi[0]] = 1.0f;
      T.v[T.bi[0]] = -1e38f;
    }
    __syncthreads();
  }
}

// ---------------- persistent mega kernel with DIY grid barriers ----------------
struct MegaArgs {
  const float* scene;
  const float* Mbuf; const float* Wvo;
  const float* ln1_g; const float* ln1_b; const float* ln2_g; const float* ln2_b;
  const float* bo; const float* W1; const float* fb1; const float* W2; const float* fb2;
  const float* mlp_W; const float* mlp_b;
  float* tq; float* qMg; float* qMb; float* ctx; float* xbuf; float* h1;
  float* xm; float* partA; float* partB; float* out;
  unsigned* cnt;
};

__global__ __launch_bounds__(256, 2) void mega(MegaArgs P) {
  __shared__ __align__(16) float smem_raw[2432];
  GemmS& G = *(GemmS*)smem_raw;
  AttnS& A = *(AttnS*)smem_raw;
  LnS& L = *(LnS*)smem_raw;
  TopS& T = *(TopS*)smem_raw;
  int bid = blockIdx.x;
  unsigned gen = 0;
#define GBAR() do { ++gen; grid_barrier(P.cnt, gen * (unsigned)GRID); } while (0)

  // layer-0 q projection
  if (bid < 64)
    dev_qln0(L, bid, P.tq, P.ln1_g, P.ln1_b, P.Mbuf, P.qMg, P.qMb);
  GBAR();

  for (int l = 0; l < LAYERS; ++l) {
    // 1. attention (all 384 blocks: b = bid/12, h = bid%12)
    dev_attn(A, P.scene, P.qMg, P.qMb, P.ln1_g, P.ln1_b, l, P.ctx, bid);
    GBAR();
    // 2. out-proj partials: 12 n-tiles x 4 k-chunks(192)
    if (bid < 48)
      dev_skinny(G, P.ctx, 768, P.Wvo + (size_t)l * 589824, 192, P.partA, 768,
                 (bid % 12) * 64, bid / 12);
    GBAR();
    // 3. x = LN1(proj + bo + tq)
    if (bid < 64)
      dev_reduce_ln_q(L, P.partA, 4, P.bo + l * 768, P.tq,
                      P.ln1_g + l * 768, P.ln1_b + l * 768, P.xbuf,
                      nullptr, nullptr, nullptr, nullptr, nullptr, nullptr, bid);
    GBAR();
    // 4. FF1 partials: 48 n-tiles x 4 k-chunks(192), N=3072
    if (bid < 192)
      dev_skinny(G, P.xbuf, 768, P.W1 + (size_t)l * FF_DIM * 768, 192, P.partB,
                 FF_DIM, (bid % 48) * 64, bid / 48);
    GBAR();
    // 5. h1 = relu(sum + b1)
    if (bid < 64)
      dev_reduce_bias(P.partB, 4, FF_DIM, P.fb1 + l * FF_DIM, 1, P.h1, bid);
    GBAR();
    // 6. FF2 partials: 12 n-tiles x 16 k-chunks(192), K=3072
    if (bid < 192)
      dev_skinny(G, P.h1, FF_DIM, P.W2 + (size_t)l * 768 * FF_DIM, 192, P.partA,
                 768, (bid % 12) * 64, bid / 12);
    GBAR();
    // 7. tq' = LN2(ff2 + b2 + x) [+ next-layer qproj | + xm accumulate at l=11]
    if (bid < 64) {
      if (l < LAYERS - 1)
        dev_reduce_ln_q(L, P.partA, 16, P.fb2 + l * 768, P.xbuf,
                        P.ln2_g + l * 768, P.ln2_b + l * 768, P.tq,
                        P.Mbuf + (l + 1) * 4096, P.ln1_g + (l + 1) * 768,
                        P.ln1_b + (l + 1) * 768, P.qMg, P.qMb, nullptr, bid);
      else
        dev_reduce_ln_q(L, P.partA, 16, P.fb2 + l * 768, P.xbuf,
                        P.ln2_g + l * 768, P.ln2_b + l * 768, P.tq,
                        nullptr, nullptr, nullptr, nullptr, nullptr, P.xm, bid);
    }
    GBAR();
  }

  // head GEMM: 16 n-tiles x 4 k-chunks(192), N=1024
  if (bid < 64)
    dev_skinny(G, P.xm, 768, P.mlp_W, 192, P.partA, 1024, (bid % 16) * 64, bid / 16);
  GBAR();
  if (bid < 32)
    dev_top5(T, P.partA, P.mlp_b, P.out, bid);
#undef GBAR
}

extern "C" void kernel_launch(void* const* d_in, const int* in_sizes, int n_in,
                              void* d_out, int out_size, void* d_ws, size_t ws_size,
                              hipStream_t stream) {
  const float* scene_masks = (const float*)d_in[0];
  const float* target_mask = (const float*)d_in[1];
  const float* emb_W = (const float*)d_in[2];
  const float* emb_b = (const float*)d_in[3];
  const float* class_embed = (const float*)d_in[4];
  const float* scene_pos = (const float*)d_in[5];
  const float* target_pos = (const float*)d_in[6];
  const float* ln1_g = (const float*)d_in[7];
  const float* ln1_b = (const float*)d_in[8];
  const float* ln2_g = (const float*)d_in[9];
  const float* ln2_b = (const float*)d_in[10];
  const float* Wq = (const float*)d_in[11];
  const float* Wk = (const float*)d_in[12];
  const float* Wv = (const float*)d_in[13];
  const float* Wo = (const float*)d_in[14];
  const float* bo = (const float*)d_in[15];
  const float* W1 = (const float*)d_in[16];
  const float* fb1 = (const float*)d_in[17];
  const float* W2 = (const float*)d_in[18];
  const float* fb2 = (const float*)d_in[19];
  const float* mlp_W = (const float*)d_in[20];
  const float* mlp_b = (const float*)d_in[21];
  float* out = (float*)d_out;

  float* ws = (float*)d_ws;
  float* scene = ws;                       // 25190400
  float* Mbuf = scene + 25190400;          // 49152
  float* Wvo = Mbuf + 49152;               // 7077888
  float* tq = Wvo + 7077888;               // 49152
  float* qMg = tq + 49152;                 // 49152
  float* qMb = qMg + 49152;                // 768
  float* ctxf = qMb + 768;                 // 49152
  float* xbuf = ctxf + 49152;              // 49152
  float* h1 = xbuf + 49152;                // 196608 (64x3072)
  float* xm = h1 + 196608;                 // 49152 (64x768, zeroed)
  float* partA = xm + 49152;               // 786432
  float* partB = partA + 786432;           // 786432
  unsigned* cnt = (unsigned*)(partB + 786432);  // barrier counter

  // ---- setup ----
  embed_gemm<<<dim3(6, 256), 256, 0, stream>>>(scene_masks, emb_W, emb_b, scene_pos, scene);
  scene_cls<<<32, 256, 0, stream>>>(class_embed, scene_pos, scene);
  ln_rows<<<32 * NTOK, 256, 0, stream>>>(scene, scene);
  tgt_init<<<32, 256, 0, stream>>>(target_mask, emb_W, emb_b, class_embed, target_pos, tq);
  prep_m<<<dim3(16, 12), 256, 0, stream>>>(Wq, Wk, Mbuf);
  prep_wvo<<<dim3(2304, 12), 256, 0, stream>>>(Wv, Wo, Wvo);
  hipMemsetAsync(xm, 0, 49152 * sizeof(float), stream);
  hipMemsetAsync(cnt, 0, 256 * sizeof(unsigned), stream);

  // ---- persistent mega: 12 layers + head ----
  MegaArgs ma;
  ma.scene = scene;
  ma.Mbuf = Mbuf; ma.Wvo = Wvo;
  ma.ln1_g = ln1_g; ma.ln1_b = ln1_b; ma.ln2_g = ln2_g; ma.ln2_b = ln2_b;
  ma.bo = bo; ma.W1 = W1; ma.fb1 = fb1; ma.W2 = W2; ma.fb2 = fb2;
  ma.mlp_W = mlp_W; ma.mlp_b = mlp_b;
  ma.tq = tq; ma.qMg = qMg; ma.qMb = qMb; ma.ctx = ctxf; ma.xbuf = xbuf;
  ma.h1 = h1; ma.xm = xm; ma.partA = partA; ma.partB = partB; ma.out = out;
  ma.cnt = cnt;
  mega<<<GRID, 256, 0, stream>>>(ma);
}